// Round 2
// baseline (296.019 us; speedup 1.0000x reference)
//
#include <hip/hip_runtime.h>

typedef unsigned short u16;
typedef unsigned int u32;
using frag8  = __attribute__((ext_vector_type(8))) short;   // 8 x bf16 (4 VGPRs)
using f32x16 = __attribute__((ext_vector_type(16))) float;  // 32x32 MFMA accumulator

// ---------- helpers ----------
__device__ __forceinline__ u16 f2bf(float f) {
  union { float f; u32 u; } x;
  x.f = f;
  u32 r = (x.u + 0x7fffu + ((x.u >> 16) & 1u)) >> 16;  // RNE
  return (u16)r;
}

// Stage a 128x32 bf16 tile (row-major, k contiguous) global -> LDS via
// async global_load_lds, width 16B. 256 threads, 2 issues each.
// LDS dest must be wave-uniform base + lane*16 (no padding!).
__device__ __forceinline__ void stage_tile(const u16* g, int ld, u16* lds, int tid) {
  const int wv = tid >> 6;
#pragma unroll
  for (int i = 0; i < 2; ++i) {
    const int c = i * 256 + tid;        // 16B chunk index, 512 total
    const int row = c >> 2;             // 4 chunks per 32-elem row
    const int col = (c & 3) * 8;        // element offset
    __builtin_amdgcn_global_load_lds(
        (const __attribute__((address_space(1))) void*)(g + (size_t)row * ld + col),
        (__attribute__((address_space(3))) void*)(lds + (size_t)(i * 256 + wv * 64) * 8),
        16, 0, 0);
  }
}

// 32x32x16 bf16 MFMA fragment read from a 128x32 LDS tile.
// A/B layout: row (m or n) = base + lane&31; k = (lane>>5)*8 + j, per k-half kh.
__device__ __forceinline__ frag8 frag_read(const u16* lds, int rowbase, int r32,
                                           int khalf, int kh) {
  return *(const frag8*)&lds[(rowbase + r32) * 32 + kh * 16 + khalf * 8];
}

// ---------- prep kernels ----------
__global__ void conv_kernel(const float* __restrict__ src, u16* __restrict__ dst, int n4) {
  int i = blockIdx.x * 256 + threadIdx.x;
  if (i >= n4) return;
  float4 v = ((const float4*)src)[i];
  ushort4 o;
  o.x = f2bf(v.x); o.y = f2bf(v.y); o.z = f2bf(v.z); o.w = f2bf(v.w);
  ((ushort4*)dst)[i] = o;
}

// all three weight matrices in one launch (blockIdx.y selects)
__global__ void convw_kernel(const float* __restrict__ s0, const float* __restrict__ s1,
                             const float* __restrict__ s2, u16* __restrict__ d0,
                             u16* __restrict__ d1, u16* __restrict__ d2, int n4) {
  int i = blockIdx.x * 256 + threadIdx.x;
  if (i >= n4) return;
  const float* src = blockIdx.y == 0 ? s0 : (blockIdx.y == 1 ? s1 : s2);
  u16* dst = blockIdx.y == 0 ? d0 : (blockIdx.y == 1 ? d1 : d2);
  float4 v = ((const float4*)src)[i];
  ushort4 o;
  o.x = f2bf(v.x); o.y = f2bf(v.y); o.z = f2bf(v.z); o.w = f2bf(v.w);
  ((ushort4*)dst)[i] = o;
}

__global__ void expw_kernel(const float* __restrict__ src, u16* __restrict__ dst, int n4) {
  int i = blockIdx.x * 256 + threadIdx.x;
  if (i >= n4) return;
  float4 v = ((const float4*)src)[i];
  ushort4 o;
  o.x = f2bf(__expf(v.x)); o.y = f2bf(__expf(v.y));
  o.z = f2bf(__expf(v.z)); o.w = f2bf(__expf(v.w));
  ((ushort4*)dst)[i] = o;
}

// C/D row map for 32x32 MFMA: row = (reg&3) + 8*(reg>>2) + 4*(lane>>5)
#define ROW32(r, khalf) (((r) & 3) + 8 * ((r) >> 2) + 4 * (khalf))

// ---------- Q projection: out = sigmoid(x @ Wq^T + bq), written to d_out ----------
__global__ __launch_bounds__(256, 3) void q_kernel(const u16* __restrict__ xb,
                                                   const u16* __restrict__ wqb,
                                                   const float* __restrict__ bq,
                                                   float* __restrict__ out) {
  __shared__ __align__(16) u16 As[128 * 32];
  __shared__ __align__(16) u16 Bs[128 * 32];
  const int tid = threadIdx.x;
  const int lane = tid & 63, wv = tid >> 6;
  const int wm = (wv & 1) * 64, wn = (wv >> 1) * 64;
  const int r32 = lane & 31, khalf = lane >> 5;
  const int m0 = blockIdx.y * 128;   // rows over B*N = 32768
  const int n0 = blockIdx.x * 128;   // cols over D = 512
  f32x16 acc[2][2] = {};
  for (int k0 = 0; k0 < 512; k0 += 32) {
    stage_tile(xb + (size_t)m0 * 512 + k0, 512, As, tid);
    stage_tile(wqb + (size_t)n0 * 512 + k0, 512, Bs, tid);
    __syncthreads();
    frag8 a[2][2], b[2][2];
#pragma unroll
    for (int ti = 0; ti < 2; ++ti)
#pragma unroll
      for (int kh = 0; kh < 2; ++kh) {
        a[ti][kh] = frag_read(As, wm + ti * 32, r32, khalf, kh);
        b[ti][kh] = frag_read(Bs, wn + ti * 32, r32, khalf, kh);
      }
#pragma unroll
    for (int ti = 0; ti < 2; ++ti)
#pragma unroll
      for (int tj = 0; tj < 2; ++tj)
#pragma unroll
        for (int kh = 0; kh < 2; ++kh)
          acc[ti][tj] = __builtin_amdgcn_mfma_f32_32x32x16_bf16(a[ti][kh], b[tj][kh],
                                                                acc[ti][tj], 0, 0, 0);
    __syncthreads();
  }
#pragma unroll
  for (int ti = 0; ti < 2; ++ti)
#pragma unroll
    for (int tj = 0; tj < 2; ++tj) {
      const int col = n0 + wn + tj * 32 + r32;
      const float bqv = bq[col];
#pragma unroll
      for (int r = 0; r < 16; ++r) {
        const int row = m0 + wm + ti * 32 + ROW32(r, khalf);
        const float qv = acc[ti][tj][r] + bqv;
        out[(size_t)row * 512 + col] = 1.0f / (1.0f + __expf(-qv));
      }
    }
}

// ---------- K,V projection (transposed out): ekT/ekvT [b][d][s] bf16 ----------
__global__ __launch_bounds__(256, 2) void kv_kernel(const u16* __restrict__ xb,
                                                    const u16* __restrict__ wkb,
                                                    const u16* __restrict__ wvb,
                                                    const float* __restrict__ bk,
                                                    const float* __restrict__ bv,
                                                    u16* __restrict__ ekT,
                                                    u16* __restrict__ ekvT) {
  __shared__ __align__(16) u16 Ak[128 * 32];
  __shared__ __align__(16) u16 Av[128 * 32];
  __shared__ __align__(16) u16 Bs[128 * 32];
  const int tid = threadIdx.x;
  const int lane = tid & 63, wv = tid >> 6;
  const int wm = (wv & 1) * 64, wn = (wv >> 1) * 64;
  const int r32 = lane & 31, khalf = lane >> 5;
  const int s0 = blockIdx.x * 128;   // n: sequence pos (1024)
  const int d0 = blockIdx.y * 128;   // m: feature dim (512)
  const int b  = blockIdx.z;
  f32x16 acck[2][2] = {}, accv[2][2] = {};
  for (int k0 = 0; k0 < 512; k0 += 32) {
    stage_tile(wkb + (size_t)d0 * 512 + k0, 512, Ak, tid);
    stage_tile(wvb + (size_t)d0 * 512 + k0, 512, Av, tid);
    stage_tile(xb + ((size_t)b * 1024 + s0) * 512 + k0, 512, Bs, tid);
    __syncthreads();
    frag8 ak[2][2], av[2][2], bb[2][2];
#pragma unroll
    for (int ti = 0; ti < 2; ++ti)
#pragma unroll
      for (int kh = 0; kh < 2; ++kh) {
        ak[ti][kh] = frag_read(Ak, wm + ti * 32, r32, khalf, kh);
        av[ti][kh] = frag_read(Av, wm + ti * 32, r32, khalf, kh);
        bb[ti][kh] = frag_read(Bs, wn + ti * 32, r32, khalf, kh);
      }
#pragma unroll
    for (int ti = 0; ti < 2; ++ti)
#pragma unroll
      for (int tj = 0; tj < 2; ++tj)
#pragma unroll
        for (int kh = 0; kh < 2; ++kh) {
          acck[ti][tj] = __builtin_amdgcn_mfma_f32_32x32x16_bf16(ak[ti][kh], bb[tj][kh],
                                                                 acck[ti][tj], 0, 0, 0);
          accv[ti][tj] = __builtin_amdgcn_mfma_f32_32x32x16_bf16(av[ti][kh], bb[tj][kh],
                                                                 accv[ti][tj], 0, 0, 0);
        }
    __syncthreads();
  }
#pragma unroll
  for (int ti = 0; ti < 2; ++ti)
#pragma unroll
    for (int r = 0; r < 16; ++r) {
      const int d = d0 + wm + ti * 32 + ROW32(r, khalf);
      const float bkv = bk[d], bvv = bv[d];
#pragma unroll
      for (int tj = 0; tj < 2; ++tj) {
        const int s = s0 + wn + tj * 32 + r32;
        const float ek = __expf(acck[ti][tj][r] + bkv);
        const float vv = accv[ti][tj][r] + bvv;
        const size_t idx = ((size_t)b * 512 + d) * 1024 + s;
        ekT[idx]  = f2bf(ek);
        ekvT[idx] = f2bf(ek * vv);
      }
    }
}

// ---------- AFT mixing: out = sigq * (EW@ekv) / (EW@ek), per batch ----------
__global__ __launch_bounds__(256, 2) void aft_kernel(const u16* __restrict__ ew,
                                                     const u16* __restrict__ ekT,
                                                     const u16* __restrict__ ekvT,
                                                     float* __restrict__ out) {
  __shared__ __align__(16) u16 As[128 * 32];
  __shared__ __align__(16) u16 B1[128 * 32];
  __shared__ __align__(16) u16 B2[128 * 32];
  const int tid = threadIdx.x;
  const int lane = tid & 63, wv = tid >> 6;
  const int wm = (wv & 1) * 64, wn = (wv >> 1) * 64;
  const int r32 = lane & 31, khalf = lane >> 5;
  const int d0 = blockIdx.x * 128;   // n: feature dim (512)
  const int t0 = blockIdx.y * 128;   // m: target pos (1024)
  const int b  = blockIdx.z;
  f32x16 accn[2][2] = {}, accd[2][2] = {};
  for (int k0 = 0; k0 < 1024; k0 += 32) {
    stage_tile(ew + (size_t)t0 * 1024 + k0, 1024, As, tid);
    stage_tile(ekvT + ((size_t)b * 512 + d0) * 1024 + k0, 1024, B1, tid);
    stage_tile(ekT + ((size_t)b * 512 + d0) * 1024 + k0, 1024, B2, tid);
    __syncthreads();
    frag8 a[2][2], b1[2][2], b2[2][2];
#pragma unroll
    for (int ti = 0; ti < 2; ++ti)
#pragma unroll
      for (int kh = 0; kh < 2; ++kh) {
        a[ti][kh]  = frag_read(As, wm + ti * 32, r32, khalf, kh);
        b1[ti][kh] = frag_read(B1, wn + ti * 32, r32, khalf, kh);
        b2[ti][kh] = frag_read(B2, wn + ti * 32, r32, khalf, kh);
      }
#pragma unroll
    for (int ti = 0; ti < 2; ++ti)
#pragma unroll
      for (int tj = 0; tj < 2; ++tj)
#pragma unroll
        for (int kh = 0; kh < 2; ++kh) {
          accn[ti][tj] = __builtin_amdgcn_mfma_f32_32x32x16_bf16(a[ti][kh], b1[tj][kh],
                                                                 accn[ti][tj], 0, 0, 0);
          accd[ti][tj] = __builtin_amdgcn_mfma_f32_32x32x16_bf16(a[ti][kh], b2[tj][kh],
                                                                 accd[ti][tj], 0, 0, 0);
        }
    __syncthreads();
  }
#pragma unroll
  for (int ti = 0; ti < 2; ++ti)
#pragma unroll
    for (int tj = 0; tj < 2; ++tj)
#pragma unroll
      for (int r = 0; r < 16; ++r) {
        const int t = t0 + wm + ti * 32 + ROW32(r, khalf);
        const int d = d0 + wn + tj * 32 + r32;
        const size_t idx = ((size_t)b * 1024 + t) * 512 + d;
        const float sq = out[idx];                    // sigmoid(q) from q_kernel
        out[idx] = sq * accn[ti][tj][r] / accd[ti][tj][r];
      }
}

// ---------- launch ----------
// Workspace layout (bytes):
//   xb   bf16[32768][512]      @ 0          (32 MB)
//   wqb  bf16[512][512]        @ 33554432
//   wkb                        @ 34078720
//   wvb                        @ 34603008
//   ewb  bf16[1024][1024]      @ 35127296   (2 MB)
//   ekT  bf16[32][512][1024]   @ 37224448   (32 MB)
//   ekvT bf16[32][512][1024]   @ 70778880   (32 MB)
// total ≈ 99.5 MB. sigmoid(q) lives in d_out (read-then-overwrite in aft_kernel).
extern "C" void kernel_launch(void* const* d_in, const int* in_sizes, int n_in,
                              void* d_out, int out_size, void* d_ws, size_t ws_size,
                              hipStream_t stream) {
  const float* x  = (const float*)d_in[0];
  const float* Wq = (const float*)d_in[1];
  const float* bq = (const float*)d_in[2];
  const float* Wk = (const float*)d_in[3];
  const float* bk = (const float*)d_in[4];
  const float* Wv = (const float*)d_in[5];
  const float* bv = (const float*)d_in[6];
  const float* pb = (const float*)d_in[7];
  float* out = (float*)d_out;
  char* ws = (char*)d_ws;
  u16* xb   = (u16*)(ws);
  u16* wqb  = (u16*)(ws + 33554432);
  u16* wkb  = (u16*)(ws + 34078720);
  u16* wvb  = (u16*)(ws + 34603008);
  u16* ewb  = (u16*)(ws + 35127296);
  u16* ekT  = (u16*)(ws + 37224448);
  u16* ekvT = (u16*)(ws + 70778880);

  conv_kernel<<<16384, 256, 0, stream>>>(x, xb, 16777216 / 4);
  convw_kernel<<<dim3(256, 3), 256, 0, stream>>>(Wq, Wk, Wv, wqb, wkb, wvb, 262144 / 4);
  expw_kernel<<<1024, 256, 0, stream>>>(pb, ewb, 1048576 / 4);

  q_kernel<<<dim3(4, 256), 256, 0, stream>>>(xb, wqb, bq, out);
  kv_kernel<<<dim3(8, 4, 32), 256, 0, stream>>>(xb, wkb, wvb, bk, bv, ekT, ekvT);
  aft_kernel<<<dim3(4, 8, 32), 256, 0, stream>>>(ewb, ekT, ekvT, out);
}

// Round 3
// 253.647 us; speedup vs baseline: 1.1671x; 1.1671x over previous
//
#include <hip/hip_runtime.h>

typedef unsigned short u16;
typedef unsigned int u32;
using frag8 = __attribute__((ext_vector_type(8))) short;   // 8 x bf16 (4 VGPRs)
using f32x4 = __attribute__((ext_vector_type(4))) float;   // 16x16 MFMA accumulator

// ---------- helpers ----------
__device__ __forceinline__ u16 f2bf(float f) {
  union { float f; u32 u; } x;
  x.f = f;
  u32 r = (x.u + 0x7fffu + ((x.u >> 16) & 1u)) >> 16;  // RNE
  return (u16)r;
}

// Stage a 128x64 bf16 tile (row-major, k contiguous) global -> LDS via async
// global_load_lds, width 16B. 256 threads, 4 issues each. LDS dest must be
// wave-uniform base + lane*16 (hardware constraint) so the LDS image is
// lane-ordered; we XOR-swizzle WHICH global chunk each lane fetches
// (colc ^ row&7) to break the 128B-row-stride bank aliasing. frag_read64
// applies the same XOR to find its data.
__device__ __forceinline__ void stage_tile64(const u16* g, int ld, u16* lds, int tid) {
  const int wv = tid >> 6;
#pragma unroll
  for (int i = 0; i < 4; ++i) {
    const int c = i * 256 + tid;              // 16B chunk index, 1024 total
    const int row = c >> 3;                   // 8 chunks per 64-elem row
    const int colc = (c & 7) ^ (row & 7);     // swizzled source chunk
    __builtin_amdgcn_global_load_lds(
        (const __attribute__((address_space(1))) void*)(g + (size_t)row * ld + colc * 8),
        (__attribute__((address_space(3))) void*)(lds + (size_t)(i * 256 + wv * 64) * 8),
        16, 0, 0);
  }
}

// 16x16x32 A/B fragment from a swizzled 128x64 tile; kk selects k-half (0/1).
__device__ __forceinline__ frag8 frag_read64(const u16* lds, int row, int kk, int quad) {
  const int cc = (kk * 4 + quad) ^ (row & 7);
  return *(const frag8*)&lds[row * 64 + cc * 8];
}

// ---------- fused prep: bf16 casts of x, Wq, Wk, Wv + exp(pos_bias) ----------
// grid.x ranges: [0,16384) x | [16384,16640) Wq | [16640,16896) Wk |
// [16896,17152) Wv | [17152,18176) exp(pos_bias)
__global__ void prep_kernel(const float* __restrict__ x, const float* __restrict__ Wq,
                            const float* __restrict__ Wk, const float* __restrict__ Wv,
                            const float* __restrict__ pb, u16* __restrict__ xb,
                            u16* __restrict__ wqb, u16* __restrict__ wkb,
                            u16* __restrict__ wvb, u16* __restrict__ ewb) {
  const int blk = blockIdx.x;
  const float* src;
  u16* dst;
  int base;
  bool ex = false;
  if (blk < 16384)      { src = x;  dst = xb;  base = blk; }
  else if (blk < 16640) { src = Wq; dst = wqb; base = blk - 16384; }
  else if (blk < 16896) { src = Wk; dst = wkb; base = blk - 16640; }
  else if (blk < 17152) { src = Wv; dst = wvb; base = blk - 16896; }
  else                  { src = pb; dst = ewb; base = blk - 17152; ex = true; }
  const int i = base * 256 + threadIdx.x;
  float4 v = ((const float4*)src)[i];
  ushort4 o;
  if (ex) {
    o.x = f2bf(__expf(v.x)); o.y = f2bf(__expf(v.y));
    o.z = f2bf(__expf(v.z)); o.w = f2bf(__expf(v.w));
  } else {
    o.x = f2bf(v.x); o.y = f2bf(v.y); o.z = f2bf(v.z); o.w = f2bf(v.w);
  }
  ((ushort4*)dst)[i] = o;
}

// ---------- Q projection: out = sigmoid(x @ Wq^T + bq), written to d_out ----------
__global__ __launch_bounds__(256, 3) void q_kernel(const u16* __restrict__ xb,
                                                   const u16* __restrict__ wqb,
                                                   const float* __restrict__ bq,
                                                   float* __restrict__ out) {
  __shared__ __align__(16) u16 As[128 * 64];
  __shared__ __align__(16) u16 Bs[128 * 64];
  const int tid = threadIdx.x;
  const int lane = tid & 63, wv = tid >> 6;
  const int wm = (wv & 1) * 64, wn = (wv >> 1) * 64;
  const int fr = lane & 15, quad = lane >> 4;
  const int m0 = blockIdx.y * 128;   // rows over B*N = 32768
  const int n0 = blockIdx.x * 128;   // cols over D = 512
  f32x4 acc[4][4] = {};
  for (int k0 = 0; k0 < 512; k0 += 64) {
    stage_tile64(xb + (size_t)m0 * 512 + k0, 512, As, tid);
    stage_tile64(wqb + (size_t)n0 * 512 + k0, 512, Bs, tid);
    __syncthreads();
#pragma unroll
    for (int kk = 0; kk < 2; ++kk) {
      frag8 a[4], b[4];
#pragma unroll
      for (int i = 0; i < 4; ++i) {
        a[i] = frag_read64(As, wm + i * 16 + fr, kk, quad);
        b[i] = frag_read64(Bs, wn + i * 16 + fr, kk, quad);
      }
#pragma unroll
      for (int mi = 0; mi < 4; ++mi)
#pragma unroll
        for (int ni = 0; ni < 4; ++ni)
          acc[mi][ni] = __builtin_amdgcn_mfma_f32_16x16x32_bf16(a[mi], b[ni], acc[mi][ni], 0, 0, 0);
    }
    __syncthreads();
  }
#pragma unroll
  for (int mi = 0; mi < 4; ++mi)
#pragma unroll
    for (int ni = 0; ni < 4; ++ni) {
      const int col = n0 + wn + ni * 16 + fr;
      const float bqv = bq[col];
#pragma unroll
      for (int r = 0; r < 4; ++r) {
        const int row = m0 + wm + mi * 16 + quad * 4 + r;
        const float qv = acc[mi][ni][r] + bqv;
        out[(size_t)row * 512 + col] = 1.0f / (1.0f + __expf(-qv));
      }
    }
}

// ---------- K,V projection (transposed out): ekT/ekvT [b][d][s] bf16 ----------
__global__ __launch_bounds__(256, 2) void kv_kernel(const u16* __restrict__ xb,
                                                    const u16* __restrict__ wkb,
                                                    const u16* __restrict__ wvb,
                                                    const float* __restrict__ bk,
                                                    const float* __restrict__ bv,
                                                    u16* __restrict__ ekT,
                                                    u16* __restrict__ ekvT) {
  __shared__ __align__(16) u16 Ak[128 * 64];
  __shared__ __align__(16) u16 Av[128 * 64];
  __shared__ __align__(16) u16 Bs[128 * 64];
  const int tid = threadIdx.x;
  const int lane = tid & 63, wv = tid >> 6;
  const int wm = (wv & 1) * 64, wn = (wv >> 1) * 64;
  const int fr = lane & 15, quad = lane >> 4;
  const int s0 = blockIdx.x * 128;   // n: sequence pos (1024)
  const int d0 = blockIdx.y * 128;   // m: feature dim (512)
  const int b  = blockIdx.z;
  f32x4 acck[4][4] = {}, accv[4][4] = {};
  for (int k0 = 0; k0 < 512; k0 += 64) {
    stage_tile64(wkb + (size_t)d0 * 512 + k0, 512, Ak, tid);
    stage_tile64(wvb + (size_t)d0 * 512 + k0, 512, Av, tid);
    stage_tile64(xb + ((size_t)b * 1024 + s0) * 512 + k0, 512, Bs, tid);
    __syncthreads();
#pragma unroll
    for (int kk = 0; kk < 2; ++kk) {
      frag8 ak[4], av[4], bb[4];
#pragma unroll
      for (int i = 0; i < 4; ++i) {
        ak[i] = frag_read64(Ak, wm + i * 16 + fr, kk, quad);
        av[i] = frag_read64(Av, wm + i * 16 + fr, kk, quad);
        bb[i] = frag_read64(Bs, wn + i * 16 + fr, kk, quad);
      }
#pragma unroll
      for (int mi = 0; mi < 4; ++mi)
#pragma unroll
        for (int ni = 0; ni < 4; ++ni) {
          acck[mi][ni] = __builtin_amdgcn_mfma_f32_16x16x32_bf16(ak[mi], bb[ni], acck[mi][ni], 0, 0, 0);
          accv[mi][ni] = __builtin_amdgcn_mfma_f32_16x16x32_bf16(av[mi], bb[ni], accv[mi][ni], 0, 0, 0);
        }
    }
    __syncthreads();
  }
#pragma unroll
  for (int mi = 0; mi < 4; ++mi)
#pragma unroll
    for (int r = 0; r < 4; ++r) {
      const int d = d0 + wm + mi * 16 + quad * 4 + r;
      const float bkv = bk[d], bvv = bv[d];
#pragma unroll
      for (int ni = 0; ni < 4; ++ni) {
        const int s = s0 + wn + ni * 16 + fr;
        const float ek = __expf(acck[mi][ni][r] + bkv);
        const float vv = accv[mi][ni][r] + bvv;
        const size_t idx = ((size_t)b * 512 + d) * 1024 + s;
        ekT[idx]  = f2bf(ek);
        ekvT[idx] = f2bf(ek * vv);
      }
    }
}

// ---------- AFT mixing: out = sigq * (EW@ekv) / (EW@ek), per batch ----------
__global__ __launch_bounds__(256, 2) void aft_kernel(const u16* __restrict__ ew,
                                                     const u16* __restrict__ ekT,
                                                     const u16* __restrict__ ekvT,
                                                     float* __restrict__ out) {
  __shared__ __align__(16) u16 As[128 * 64];
  __shared__ __align__(16) u16 B1[128 * 64];
  __shared__ __align__(16) u16 B2[128 * 64];
  const int tid = threadIdx.x;
  const int lane = tid & 63, wv = tid >> 6;
  const int wm = (wv & 1) * 64, wn = (wv >> 1) * 64;
  const int fr = lane & 15, quad = lane >> 4;
  const int d0 = blockIdx.x * 128;   // n: feature dim (512)
  const int t0 = blockIdx.y * 128;   // m: target pos (1024)
  const int b  = blockIdx.z;
  f32x4 accn[4][4] = {}, accd[4][4] = {};
  for (int k0 = 0; k0 < 1024; k0 += 64) {
    stage_tile64(ew + (size_t)t0 * 1024 + k0, 1024, As, tid);
    stage_tile64(ekvT + ((size_t)b * 512 + d0) * 1024 + k0, 1024, B1, tid);
    stage_tile64(ekT + ((size_t)b * 512 + d0) * 1024 + k0, 1024, B2, tid);
    __syncthreads();
#pragma unroll
    for (int kk = 0; kk < 2; ++kk) {
      frag8 a[4], b1[4], b2[4];
#pragma unroll
      for (int i = 0; i < 4; ++i) {
        a[i]  = frag_read64(As, wm + i * 16 + fr, kk, quad);
        b1[i] = frag_read64(B1, wn + i * 16 + fr, kk, quad);
        b2[i] = frag_read64(B2, wn + i * 16 + fr, kk, quad);
      }
#pragma unroll
      for (int mi = 0; mi < 4; ++mi)
#pragma unroll
        for (int ni = 0; ni < 4; ++ni) {
          accn[mi][ni] = __builtin_amdgcn_mfma_f32_16x16x32_bf16(a[mi], b1[ni], accn[mi][ni], 0, 0, 0);
          accd[mi][ni] = __builtin_amdgcn_mfma_f32_16x16x32_bf16(a[mi], b2[ni], accd[mi][ni], 0, 0, 0);
        }
    }
    __syncthreads();
  }
#pragma unroll
  for (int mi = 0; mi < 4; ++mi)
#pragma unroll
    for (int ni = 0; ni < 4; ++ni)
#pragma unroll
      for (int r = 0; r < 4; ++r) {
        const int t = t0 + wm + mi * 16 + quad * 4 + r;
        const int d = d0 + wn + ni * 16 + fr;
        const size_t idx = ((size_t)b * 1024 + t) * 512 + d;
        const float sq = out[idx];                    // sigmoid(q) from q_kernel
        out[idx] = sq * accn[mi][ni][r] / accd[mi][ni][r];
      }
}

// ---------- launch ----------
// Workspace layout (bytes):
//   xb   bf16[32768][512]      @ 0          (32 MB)
//   wqb  bf16[512][512]        @ 33554432
//   wkb                        @ 34078720
//   wvb                        @ 34603008
//   ewb  bf16[1024][1024]      @ 35127296   (2 MB)
//   ekT  bf16[32][512][1024]   @ 37224448   (32 MB)
//   ekvT bf16[32][512][1024]   @ 70778880   (32 MB)
// total ≈ 99.5 MB. sigmoid(q) lives in d_out (read-then-overwrite in aft_kernel).
extern "C" void kernel_launch(void* const* d_in, const int* in_sizes, int n_in,
                              void* d_out, int out_size, void* d_ws, size_t ws_size,
                              hipStream_t stream) {
  const float* x  = (const float*)d_in[0];
  const float* Wq = (const float*)d_in[1];
  const float* bq = (const float*)d_in[2];
  const float* Wk = (const float*)d_in[3];
  const float* bk = (const float*)d_in[4];
  const float* Wv = (const float*)d_in[5];
  const float* bv = (const float*)d_in[6];
  const float* pb = (const float*)d_in[7];
  float* out = (float*)d_out;
  char* ws = (char*)d_ws;
  u16* xb   = (u16*)(ws);
  u16* wqb  = (u16*)(ws + 33554432);
  u16* wkb  = (u16*)(ws + 34078720);
  u16* wvb  = (u16*)(ws + 34603008);
  u16* ewb  = (u16*)(ws + 35127296);
  u16* ekT  = (u16*)(ws + 37224448);
  u16* ekvT = (u16*)(ws + 70778880);

  prep_kernel<<<18176, 256, 0, stream>>>(x, Wq, Wk, Wv, pb, xb, wqb, wkb, wvb, ewb);
  q_kernel<<<dim3(4, 256), 256, 0, stream>>>(xb, wqb, bq, out);
  kv_kernel<<<dim3(8, 4, 32), 256, 0, stream>>>(xb, wkb, wvb, bk, bv, ekT, ekvT);
  aft_kernel<<<dim3(4, 8, 32), 256, 0, stream>>>(ewb, ekT, ekvT, out);
}